// Round 10
// baseline (225.323 us; speedup 1.0000x reference)
//
#include <hip/hip_runtime.h>
#include <math.h>

#define BB 32768
#define DD 512
#define CC 527
#define NCOLP 576   // padded W cols in Wbf
#define BM 64       // rows per GEMM block
#define ZSH 552     // LDS z row stride (u16): 1104 B, 16B-aligned
#define XST 520     // LDS x row stride (bf16)
#define XBYTES (BM * XST * 2)       // 66,560
#define ZBYTES (BM * ZSH * 2)       // 70,656
#define SMEMB  (XBYTES + ZBYTES)    // 137,216 (fused fallback only)
#define GSMEMB ZBYTES               // 70,656: gemm x/z UNION -> 2 blocks/CU
#define ZGS 528     // global z row stride (u16)

typedef __attribute__((ext_vector_type(8))) short bf16x8;
typedef __attribute__((ext_vector_type(4))) short bf16x4;
typedef __attribute__((ext_vector_type(4))) float f32x4;
typedef __attribute__((ext_vector_type(4))) unsigned int u32x4;
typedef f32x4 f32x4u __attribute__((aligned(4)));   // y rows only 4B-aligned

#define C4(OP)  OP(0) OP(1) OP(2) OP(3)

#if __has_builtin(__builtin_amdgcn_exp2f)
#define EXP2F(v) __builtin_amdgcn_exp2f(v)
#else
#define EXP2F(v) exp2f(v)
#endif
#if __has_builtin(__builtin_amdgcn_logf)
#define LOG2F(v) __builtin_amdgcn_logf(v)
#else
#define LOG2F(v) __log2f(v)
#endif

__device__ __forceinline__ short f2bf(float f) {  // fp32 -> bf16 RNE
  unsigned u = __float_as_uint(f);
  u += 0x7fffu + ((u >> 16) & 1u);
  return (short)(u >> 16);
}
__device__ __forceinline__ bf16x8 pack8(f32x4 a, f32x4 b) {
  bf16x8 v;
  v[0]=f2bf(a.x); v[1]=f2bf(a.y); v[2]=f2bf(a.z); v[3]=f2bf(a.w);
  v[4]=f2bf(b.x); v[5]=f2bf(b.y); v[6]=f2bf(b.z); v[7]=f2bf(b.w);
  return v;
}
__device__ __forceinline__ unsigned cvtpk(float lo, float hi) {
  unsigned r;
  asm volatile("v_cvt_pk_bf16_f32 %0, %1, %2" : "=v"(r) : "v"(lo), "v"(hi));
  return r;
}

// 16-lane (DPP row) reductions: 4 x row_ror, pure VALU.
__device__ __forceinline__ int dppadd16(int v) {
  v += __builtin_amdgcn_update_dpp(0, v, 0x121, 0xf, 0xf, false);
  v += __builtin_amdgcn_update_dpp(0, v, 0x122, 0xf, 0xf, false);
  v += __builtin_amdgcn_update_dpp(0, v, 0x124, 0xf, 0xf, false);
  v += __builtin_amdgcn_update_dpp(0, v, 0x128, 0xf, 0xf, false);
  return v;
}
__device__ __forceinline__ int dppmax16i(int v) {
  int t;
  t = __builtin_amdgcn_update_dpp(0, v, 0x121, 0xf, 0xf, false); v = v > t ? v : t;
  t = __builtin_amdgcn_update_dpp(0, v, 0x122, 0xf, 0xf, false); v = v > t ? v : t;
  t = __builtin_amdgcn_update_dpp(0, v, 0x124, 0xf, 0xf, false); v = v > t ? v : t;
  t = __builtin_amdgcn_update_dpp(0, v, 0x128, 0xf, 0xf, false); v = v > t ? v : t;
  return v;
}

// bf16 bits -> order-preserving u16, then (mono<<10)|col: tie-free total order.
#define KEYOF(b, idx) ((int)(((((unsigned)(b)) ^ (0x8000u | (0xFFFFu * (((unsigned)(b)) >> 15)))) << 10) | (unsigned)(idx)))

// ============================ SPLIT PATH =====================================
// r9: gemm_part at 137KB LDS = 1 block/CU -> the 2 sequential blocks per CU
// fully serialize (incl. drains); 80% stall. v2: 512 thr (8 waves), x/z LDS
// UNION (70.6KB, r4-r6-verified barrier pattern) -> 2 resident blocks overlap
// phases. Wave = 4 tiles x 4 rowsets (B feeds 4 MFMAs, same per-row VMEM);
// tiles 0-1 depth-2, 2-3 depth-1 (fits (512,4)=128-reg budget); tile 32 in a
// separate mini K-loop on waves 6/7 after the main loop (xs still valid) ->
// branch-free main loop, lower live-set.

// ---- pass 1: GEMM ----
__global__ __launch_bounds__(512, 4)
void gemm_part(const float* __restrict__ x, const short* __restrict__ Wbf,
               const float* __restrict__ bias, unsigned short* __restrict__ zg) {
  extern __shared__ __align__(16) char smem[];
  unsigned short* xs = (unsigned short*)smem;   // [BM][XST] bf16 (pre-barrier)
  unsigned short* zs = (unsigned short*)smem;   // [BM][ZSH] bf16 (post-barrier union)

  const int tid  = threadIdx.x;
  const int w    = tid >> 6, lane = tid & 63;
  const int cl   = lane & 15, quad = lane >> 4;
  const int row0 = blockIdx.x * BM;

  // x -> LDS as bf16 (coalesced, cvt_pk): 64x512 f32, 16 iters x 512thr x f32x4
  {
    const float* xblk = x + (size_t)row0 * DD;
#pragma unroll
    for (int i = 0; i < 16; ++i) {
      const int e = i * 2048 + tid * 4;
      f32x4 v = *(const f32x4*)(xblk + e);
      const int r = e >> 9, c = e & 511;
      const unsigned w0 = cvtpk(v.x, v.y), w1 = cvtpk(v.z, v.w);
      const unsigned long long ww = (unsigned long long)w0 |
                                    ((unsigned long long)w1 << 32);
      *(unsigned long long*)(xs + r * XST + c) = ww;
    }
  }
  __syncthreads();

  // wave w owns tiles 4w..4w+3 (cols < 512 always); tile 32 -> waves 6/7 later
  const int c0 = (4 * w + 0) * 16 + cl;
  const int c1 = (4 * w + 1) * 16 + cl;
  const int c2 = (4 * w + 2) * 16 + cl;
  const int c3 = (4 * w + 3) * 16 + cl;

#define DECLT(j) f32x4 P##j##0 = (f32x4){0.f,0.f,0.f,0.f}; \
                 f32x4 P##j##1 = (f32x4){0.f,0.f,0.f,0.f}; \
                 f32x4 P##j##2 = (f32x4){0.f,0.f,0.f,0.f}; \
                 f32x4 P##j##3 = (f32x4){0.f,0.f,0.f,0.f};
  DECLT(0) DECLT(1) DECLT(2) DECLT(3)
#undef DECLT

#define MFT(j, bj) { \
    P##j##0 = __builtin_amdgcn_mfma_f32_16x16x32_bf16(a0, bj, P##j##0, 0, 0, 0); \
    P##j##1 = __builtin_amdgcn_mfma_f32_16x16x32_bf16(a1, bj, P##j##1, 0, 0, 0); \
    P##j##2 = __builtin_amdgcn_mfma_f32_16x16x32_bf16(a2, bj, P##j##2, 0, 0, 0); \
    P##j##3 = __builtin_amdgcn_mfma_f32_16x16x32_bf16(a3, bj, P##j##3, 0, 0, 0); }

  const unsigned short* xr = xs + (size_t)cl * XST + quad * 8;
  {
    const short* wb0 = Wbf + (size_t)c0 * DD + quad * 8;
    const short* wb1 = Wbf + (size_t)c1 * DD + quad * 8;
    const short* wb2 = Wbf + (size_t)c2 * DD + quad * 8;
    const short* wb3 = Wbf + (size_t)c3 * DD + quad * 8;
    // depth-2 pipeline on tiles 0,1
    bf16x8 b0c = *(const bf16x8*)(wb0);
    bf16x8 b1c = *(const bf16x8*)(wb1);
    bf16x8 b0n = *(const bf16x8*)(wb0 + 32);
    bf16x8 b1n = *(const bf16x8*)(wb1 + 32);
#pragma unroll 1
    for (int k0 = 0; k0 < DD; k0 += 32) {
      bf16x8 a0 = *(const bf16x8*)(xr + k0);
      bf16x8 a1 = *(const bf16x8*)(xr + 16 * XST + k0);
      bf16x8 a2 = *(const bf16x8*)(xr + 32 * XST + k0);
      bf16x8 a3 = *(const bf16x8*)(xr + 48 * XST + k0);
      bf16x8 u0 = b0c, u1 = b1c;
      b0c = b0n; b1c = b1n;
      if (k0 < DD - 64) {
        b0n = *(const bf16x8*)(wb0 + k0 + 64);
        b1n = *(const bf16x8*)(wb1 + k0 + 64);
      }
      // depth-1 on tiles 2,3 (issued before the MFMA wall of tiles 0,1)
      bf16x8 u2 = *(const bf16x8*)(wb2 + k0);
      bf16x8 u3 = *(const bf16x8*)(wb3 + k0);
      MFT(0, u0)
      MFT(1, u1)
      MFT(2, u2)
      MFT(3, u3)
    }
  }

  // tile 32 (cols 512..527): mini K-loop on waves 6/7 only; xs still valid.
  const bool tA = (w == 6), tB = (w == 7);   // rowsets {0,1} / {2,3}
  f32x4 Ra = (f32x4){0.f,0.f,0.f,0.f};
  f32x4 Rb = (f32x4){0.f,0.f,0.f,0.f};
  if (tA || tB) {
    const short* wb4 = Wbf + (size_t)(512 + cl) * DD + quad * 8;  // rows>=CC zeroed
    const unsigned short* xrT = xr + (tB ? 32 * XST : 0);
#pragma unroll 1
    for (int k0 = 0; k0 < DD; k0 += 32) {
      bf16x8 b4 = *(const bf16x8*)(wb4 + k0);
      bf16x8 aa = *(const bf16x8*)(xrT + k0);
      bf16x8 ab = *(const bf16x8*)(xrT + 16 * XST + k0);
      Ra = __builtin_amdgcn_mfma_f32_16x16x32_bf16(aa, b4, Ra, 0, 0, 0);
      Rb = __builtin_amdgcn_mfma_f32_16x16x32_bf16(ab, b4, Rb, 0, 0, 0);
    }
  }
#undef MFT

  const float bt0 = bias[c0];
  const float bt1 = bias[c1];
  const float bt2 = bias[c2];
  const float bt3 = bias[c3];
  const float bt4 = ((tA || tB) && cl < 15) ? bias[512 + cl] : 0.f;

  __syncthreads();   // all A-reads done; union region becomes z

  // z (+bias) -> LDS as bf16 via cvt_pk (transpose)
#define WRP(P, rbase, colv, btv) { \
    const unsigned p01 = cvtpk(P[0] + (btv), P[1] + (btv)); \
    const unsigned p23 = cvtpk(P[2] + (btv), P[3] + (btv)); \
    const int rr = (rbase) + quad * 4; \
    zs[(rr + 0) * ZSH + (colv)] = (unsigned short)p01; \
    zs[(rr + 1) * ZSH + (colv)] = (unsigned short)(p01 >> 16); \
    zs[(rr + 2) * ZSH + (colv)] = (unsigned short)p23; \
    zs[(rr + 3) * ZSH + (colv)] = (unsigned short)(p23 >> 16); }
  WRP(P00, 0, c0, bt0) WRP(P01, 16, c0, bt0) WRP(P02, 32, c0, bt0) WRP(P03, 48, c0, bt0)
  WRP(P10, 0, c1, bt1) WRP(P11, 16, c1, bt1) WRP(P12, 32, c1, bt1) WRP(P13, 48, c1, bt1)
  WRP(P20, 0, c2, bt2) WRP(P21, 16, c2, bt2) WRP(P22, 32, c2, bt2) WRP(P23, 48, c2, bt2)
  WRP(P30, 0, c3, bt3) WRP(P31, 16, c3, bt3) WRP(P32, 32, c3, bt3) WRP(P33, 48, c3, bt3)
  if (tA)      { WRP(Ra, 0,  512 + cl, bt4) WRP(Rb, 16, 512 + cl, bt4) }
  else if (tB) { WRP(Ra, 32, 512 + cl, bt4) WRP(Rb, 48, 512 + cl, bt4) }
#undef WRP

  __syncthreads();

  // coalesced copy-out: 64 rows x 528 u16 -> zg; 4224 x4-chunks (66/row)
  for (int i = tid; i < 4224; i += 512) {
    const int r = i / 66, c = i % 66;
    u32x4 v = *(const u32x4*)(zs + r * ZSH + c * 8);
    *(u32x4*)(zg + (size_t)(row0 + r) * ZGS + c * 8) = v;
  }
}

// ---- pass 2: epilogue (r9-verified verbatim) ----
__global__ __launch_bounds__(512, 6)
void epi_part(const unsigned short* __restrict__ zg, const float* __restrict__ y,
              const float* __restrict__ pw, float* __restrict__ accum) {
  __shared__ float redL[8], redS[8];
  const int tid  = threadIdx.x;
  const int w    = tid >> 6, lane = tid & 63;
  const int cl   = lane & 15, quad = lane >> 4;
  const int erow = blockIdx.x * 32 + w * 4 + quad;

  const unsigned short* zrow = zg + (size_t)erow * ZGS;
  const float* yrow = y + (size_t)erow * CC;

#define KDECL(t) int K##t##_0, K##t##_1, K##t##_2, K##t##_3, K##t##_4, K##t##_5, K##t##_6, K##t##_7;
  C4(KDECL)
#undef KDECL
  int K32 = 0;
  unsigned ym0 = 0, ym1 = 0;
  float lossloc = 0.f;

#define LE(t, e) { \
    unsigned b = (((e) & 1) ? (zr[(e) >> 1] >> 16) : (zr[(e) >> 1] & 0xFFFFu)); \
    float z = __uint_as_float(b << 16); \
    float yv = ((e) < 4) ? ya[(e)] : yb[(e) - 4]; \
    float pv = ((e) < 4) ? pa[(e)] : pb[(e) - 4]; \
    float l1 = LOG2F(1.f + EXP2F(fabsf(z) * -1.4426950408889634f)) * 0.6931471805599453f; \
    float sp = fmaxf(z, 0.f) + l1; \
    lossloc += pv * yv * (sp - z) + (1.f - yv) * sp; \
    if (yv > 0.5f) ym0 |= (1u << (8*(t)+(e))); \
    K##t##_##e = KEYOF(b, 128*(t) + 8*cl + (e)); }
#define LCH(t) { \
    u32x4 zr = *(const u32x4*)&zrow[128*(t) + 8*cl]; \
    f32x4 ya = (f32x4)(*(const f32x4u*)(yrow + 128*(t) + 8*cl)); \
    f32x4 yb = (f32x4)(*(const f32x4u*)(yrow + 128*(t) + 8*cl + 4)); \
    f32x4 pa = *(const f32x4*)(pw + 128*(t) + 8*cl); \
    f32x4 pb = *(const f32x4*)(pw + 128*(t) + 8*cl + 4); \
    LE(t,0) LE(t,1) LE(t,2) LE(t,3) LE(t,4) LE(t,5) LE(t,6) LE(t,7) }
  C4(LCH)
#undef LCH
#undef LE
  if (cl < 15) {              // tail cols 512..526
    const int col = 512 + cl;
    unsigned b = zrow[col];
    float z = __uint_as_float(b << 16);
    float yv = yrow[col];
    float pv = pw[col];
    float l1 = LOG2F(1.f + EXP2F(fabsf(z) * -1.4426950408889634f)) * 0.6931471805599453f;
    float sp = fmaxf(z, 0.f) + l1;
    lossloc += pv * yv * (sp - z) + (1.f - yv) * sp;
    if (yv > 0.5f) ym1 = 1u;
    K32 = KEYOF(b, col);
  }

  const int kk = dppadd16(__popc(ym0) + (int)ym1);

  int mxK = K32;
#define MXK(t) { int m01 = K##t##_0 > K##t##_1 ? K##t##_0 : K##t##_1; \
    int m23 = K##t##_2 > K##t##_3 ? K##t##_2 : K##t##_3; \
    int m45 = K##t##_4 > K##t##_5 ? K##t##_4 : K##t##_5; \
    int m67 = K##t##_6 > K##t##_7 ? K##t##_6 : K##t##_7; \
    int ma = m01 > m23 ? m01 : m23; int mb = m45 > m67 ? m45 : m67; \
    int mc = ma > mb ? ma : mb; mxK = mxK > mc ? mxK : mc; }
  C4(MXK)
#undef MXK
  mxK = dppmax16i(mxK);

  int lo = -1, hi = mxK, th = 0;
  bool fnd = false;
#pragma unroll 1
  for (int it = 0; it < 32; ++it) {
    const int tm = (lo + hi) >> 1;
    int c = (K32 > tm);
#define CK(t) c += (K##t##_0 > tm) + (K##t##_1 > tm) + (K##t##_2 > tm) + (K##t##_3 > tm) \
             + (K##t##_4 > tm) + (K##t##_5 > tm) + (K##t##_6 > tm) + (K##t##_7 > tm);
    C4(CK)
#undef CK
    c = dppadd16(c);
    if (!fnd) {
      if (c == kk)                   { th = tm; fnd = true; }
      else if (tm <= lo || tm >= hi) { th = lo; fnd = true; }
      else if (c > kk)               lo = tm;
      else                           hi = tm;
    }
    if (__all(fnd)) break;
  }
  if (!fnd) th = lo;

  int h = (int)(ym1 & (unsigned)(K32 > th));
#define HT(t) h += (int)((ym0 >> (8*(t)+0)) & 1u) & (int)(K##t##_0 > th); \
  h += (int)((ym0 >> (8*(t)+1)) & 1u) & (int)(K##t##_1 > th); \
  h += (int)((ym0 >> (8*(t)+2)) & 1u) & (int)(K##t##_2 > th); \
  h += (int)((ym0 >> (8*(t)+3)) & 1u) & (int)(K##t##_3 > th); \
  h += (int)((ym0 >> (8*(t)+4)) & 1u) & (int)(K##t##_4 > th); \
  h += (int)((ym0 >> (8*(t)+5)) & 1u) & (int)(K##t##_5 > th); \
  h += (int)((ym0 >> (8*(t)+6)) & 1u) & (int)(K##t##_6 > th); \
  h += (int)((ym0 >> (8*(t)+7)) & 1u) & (int)(K##t##_7 > th);
  C4(HT)
#undef HT
  h = dppadd16(h);

  float scoreloc = 0.f;
  if (cl == 0) {
    const int hv = h < kk ? h : kk;
    scoreloc = (float)hv / (float)kk;
  }

#pragma unroll
  for (int m = 1; m < 64; m <<= 1) {
    lossloc  += __shfl_xor(lossloc, m, 64);
    scoreloc += __shfl_xor(scoreloc, m, 64);
  }
  if (lane == 0) { redL[w] = lossloc; redS[w] = scoreloc; }
  __syncthreads();
  if (tid == 0) {
    float sl = 0.f, ss = 0.f;
#pragma unroll
    for (int i = 0; i < 8; ++i) { sl += redL[i]; ss += redS[i]; }
    atomicAdd(&accum[0], sl);
    atomicAdd(&accum[1], ss);
  }
}

// ======================== FUSED FALLBACK (r8, verified) ======================
template<bool PRE>
__global__ __launch_bounds__(1024, 4)
void fused_mfma_bce_topk(const float* __restrict__ x, const float* __restrict__ y,
                         const float* __restrict__ W, const short* __restrict__ Wbf,
                         const float* __restrict__ bias, const float* __restrict__ pw,
                         float* __restrict__ accum) {
  extern __shared__ __align__(16) char smem[];
  unsigned short* xs = (unsigned short*)smem;
  unsigned short* zs = (unsigned short*)(smem + XBYTES);
  __shared__ float redL[16], redS[16];

  const int tid  = threadIdx.x;
  const int w    = tid >> 6, lane = tid & 63;
  const int cl   = lane & 15, quad = lane >> 4;
  const int row0 = blockIdx.x * BM;

  {
    const float* xblk = x + (size_t)row0 * DD;
#pragma unroll
    for (int i = 0; i < 8; ++i) {
      const int e = i * 4096 + tid * 4;
      f32x4 v = *(const f32x4*)(xblk + e);
      const int r = e >> 9, c = e & 511;
      const unsigned w0 = cvtpk(v.x, v.y), w1 = cvtpk(v.z, v.w);
      const unsigned long long ww = (unsigned long long)w0 |
                                    ((unsigned long long)w1 << 32);
      *(unsigned long long*)(xs + r * XST + c) = ww;
    }
  }
  __syncthreads();

  const bool tA = (w == 14), tB = (w == 15);
  const int c0 = (2 * w) * 16 + cl;
  const int c1 = c0 + 16;
  const int c2 = 512 + cl;

#define DECLT(j) f32x4 P##j##0 = (f32x4){0.f,0.f,0.f,0.f}; \
                 f32x4 P##j##1 = (f32x4){0.f,0.f,0.f,0.f}; \
                 f32x4 P##j##2 = (f32x4){0.f,0.f,0.f,0.f}; \
                 f32x4 P##j##3 = (f32x4){0.f,0.f,0.f,0.f};
  DECLT(0) DECLT(1)
#undef DECLT
  f32x4 Ra = (f32x4){0.f,0.f,0.f,0.f};
  f32x4 Rb = (f32x4){0.f,0.f,0.f,0.f};

#define MFT(j, bj) { \
    P##j##0 = __builtin_amdgcn_mfma_f32_16x16x32_bf16(a0, bj, P##j##0, 0, 0, 0); \
    P##j##1 = __builtin_amdgcn_mfma_f32_16x16x32_bf16(a1, bj, P##j##1, 0, 0, 0); \
    P##j##2 = __builtin_amdgcn_mfma_f32_16x16x32_bf16(a2, bj, P##j##2, 0, 0, 0); \
    P##j##3 = __builtin_amdgcn_mfma_f32_16x16x32_bf16(a3, bj, P##j##3, 0, 0, 0); }

  const unsigned short* xr = xs + (size_t)cl * XST + quad * 8;

  if (PRE) {
    const short* wb0 = Wbf + (size_t)c0 * DD + quad * 8;
    const short* wb1 = Wbf + (size_t)c1 * DD + quad * 8;
    const short* wb2 = Wbf + (size_t)c2 * DD + quad * 8;
    bf16x8 b0c = *(const bf16x8*)(wb0);
    bf16x8 b1c = *(const bf16x8*)(wb1);
    bf16x8 b0n = *(const bf16x8*)(wb0 + 32);
    bf16x8 b1n = *(const bf16x8*)(wb1 + 32);
    bf16x8 b2c = {0,0,0,0,0,0,0,0}, b2n = {0,0,0,0,0,0,0,0};
    if (tA || tB) {
      b2c = *(const bf16x8*)(wb2);
      b2n = *(const bf16x8*)(wb2 + 32);
    }
#pragma unroll 1
    for (int k0 = 0; k0 < DD; k0 += 32) {
      bf16x8 a0 = *(const bf16x8*)(xr + k0);
      bf16x8 a1 = *(const bf16x8*)(xr + 16 * XST + k0);
      bf16x8 a2 = *(const bf16x8*)(xr + 32 * XST + k0);
      bf16x8 a3 = *(const bf16x8*)(xr + 48 * XST + k0);
      bf16x8 u0 = b0c, u1 = b1c;
      b0c = b0n; b1c = b1n;
      if (k0 < DD - 64) {
        b0n = *(const bf16x8*)(wb0 + k0 + 64);
        b1n = *(const bf16x8*)(wb1 + k0 + 64);
      }
      MFT(0, u0)
      MFT(1, u1)
      if (tA || tB) {
        bf16x8 u2 = b2c;
        b2c = b2n;
        if (k0 < DD - 64) b2n = *(const bf16x8*)(wb2 + k0 + 64);
        if (tA) {
          Ra = __builtin_amdgcn_mfma_f32_16x16x32_bf16(a0, u2, Ra, 0, 0, 0);
          Rb = __builtin_amdgcn_mfma_f32_16x16x32_bf16(a1, u2, Rb, 0, 0, 0);
        } else {
          Ra = __builtin_amdgcn_mfma_f32_16x16x32_bf16(a2, u2, Ra, 0, 0, 0);
          Rb = __builtin_amdgcn_mfma_f32_16x16x32_bf16(a3, u2, Rb, 0, 0, 0);
        }
      }
    }
  } else {
    for (int k0 = 0; k0 < DD; k0 += 32) {
      bf16x8 a0 = *(const bf16x8*)(xr + k0);
      bf16x8 a1 = *(const bf16x8*)(xr + 16 * XST + k0);
      bf16x8 a2 = *(const bf16x8*)(xr + 32 * XST + k0);
      bf16x8 a3 = *(const bf16x8*)(xr + 48 * XST + k0);
      bf16x8 b0, b1;
      { const float* wp = W + (size_t)c0 * DD + k0 + quad * 8;
        b0 = pack8(*(const f32x4*)wp, *(const f32x4*)(wp + 4)); }
      { const float* wp = W + (size_t)c1 * DD + k0 + quad * 8;
        b1 = pack8(*(const f32x4*)wp, *(const f32x4*)(wp + 4)); }
      MFT(0, b0)
      MFT(1, b1)
      if (tA || tB) {
        bf16x8 b2 = {0,0,0,0,0,0,0,0};
        if (c2 < CC) {
          const float* wp = W + (size_t)c2 * DD + k0 + quad * 8;
          b2 = pack8(*(const f32x4*)wp, *(const f32x4*)(wp + 4));
        }
        if (tA) {
          Ra = __builtin_amdgcn_mfma_f32_16x16x32_bf16(a0, b2, Ra, 0, 0, 0);
          Rb = __builtin_amdgcn_mfma_f32_16x16x32_bf16(a1, b2, Rb, 0, 0, 0);
        } else {
          Ra = __builtin_amdgcn_mfma_f32_16x16x32_bf16(a2, b2, Ra, 0, 0, 0);
          Rb = __builtin_amdgcn_mfma_f32_16x16x32_bf16(a3, b2, Rb, 0, 0, 0);
        }
      }
    }
  }
#undef MFT

  const int erow = w * 4 + quad;
  const float* yrow = y + (size_t)erow * CC + (size_t)row0 * CC;
#define LYP(t) f32x4 YA##t = (f32x4)(*(const f32x4u*)(yrow + 128*(t) + 8*cl)); \
               f32x4 YB##t = (f32x4)(*(const f32x4u*)(yrow + 128*(t) + 8*cl + 4));
  C4(LYP)
#undef LYP
  float ytail = (cl < 15) ? yrow[512 + cl] : 0.f;

  const float bt0 = bias[c0];
  const float bt1 = bias[c1];
  const float bt2 = ((tA || tB) && cl < 15) ? bias[c2] : 0.f;

#define WRP(P, rbase, colv, btv) { \
    const unsigned p01 = cvtpk(P[0] + (btv), P[1] + (btv)); \
    const unsigned p23 = cvtpk(P[2] + (btv), P[3] + (btv)); \
    const int rr = (rbase) + quad * 4; \
    zs[(rr + 0) * ZSH + (colv)] = (unsigned short)p01; \
    zs[(rr + 1) * ZSH + (colv)] = (unsigned short)(p01 >> 16); \
    zs[(rr + 2) * ZSH + (colv)] = (unsigned short)p23; \
    zs[(rr + 3) * ZSH + (colv)] = (unsigned short)(p23 >> 16); }
  WRP(P00, 0, c0, bt0) WRP(P01, 16, c0, bt0) WRP(P02, 32, c0, bt0) WRP(P03, 48, c0, bt0)
  WRP(P10, 0, c1, bt1) WRP(P11, 16, c1, bt1) WRP(P12, 32, c1, bt1) WRP(P13, 48, c1, bt1)
  if (tA)      { WRP(Ra, 0, c2, bt2)  WRP(Rb, 16, c2, bt2) }
  else if (tB) { WRP(Ra, 32, c2, bt2) WRP(Rb, 48, c2, bt2) }
#undef WRP

  __syncthreads();

  const unsigned short* zrow = zs + (size_t)erow * ZSH;

#define KDECL(t) int K##t##_0, K##t##_1, K##t##_2, K##t##_3, K##t##_4, K##t##_5, K##t##_6, K##t##_7;
  C4(KDECL)
#undef KDECL
  int K32 = 0;
  unsigned ym0 = 0, ym1 = 0;
  float lossloc = 0.f;

#define LE(t, e) { \
    unsigned b = (((e) & 1) ? (zr[(e) >> 1] >> 16) : (zr[(e) >> 1] & 0xFFFFu)); \
    float z = __uint_as_float(b << 16); \
    float yv = ((e) < 4) ? YA##t[(e)] : YB##t[(e) - 4]; \
    float pv = ((e) < 4) ? pa[(e)] : pb[(e) - 4]; \
    float l1 = LOG2F(1.f + EXP2F(fabsf(z) * -1.4426950408889634f)) * 0.6931471805599453f; \
    float sp = fmaxf(z, 0.f) + l1; \
    lossloc += pv * yv * (sp - z) + (1.f - yv) * sp; \
    if (yv > 0.5f) ym0 |= (1u << (8*(t)+(e))); \
    K##t##_##e = KEYOF(b, 128*(t) + 8*cl + (e)); }
#define LCH(t) { \
    u32x4 zr = *(const u32x4*)&zrow[128*(t) + 8*cl]; \
    f32x4 pa = *(const f32x4*)(pw + 128*(t) + 8*cl); \
    f32x4 pb = *(const f32x4*)(pw + 128*(t) + 8*cl + 4); \
    LE(t,0) LE(t,1) LE(t,2) LE(t,3) LE(t,4) LE(t,5) LE(t,6) LE(t,7) }
  C4(LCH)
#undef LCH
#undef LE
  if (cl < 15) {
    const int col = 512 + cl;
    unsigned b = zrow[col];
    float z = __uint_as_float(b << 16);
    float yv = ytail;
    float pv = pw[col];
    float l1 = LOG2F(1.f + EXP2F(fabsf(z) * -1.4426950408889634f)) * 0.6931471805599453f;
    float sp = fmaxf(z, 0.f) + l1;
    lossloc += pv * yv * (sp - z) + (1.f - yv) * sp;
    if (yv > 0.5f) ym1 = 1u;
    K32 = KEYOF(b, col);
  }

  const int kk = dppadd16(__popc(ym0) + (int)ym1);

  int mxK = K32;
#define MXK(t) { int m01 = K##t##_0 > K##t##_1 ? K##t##_0 : K##t##_1; \
    int m23 = K##t##_2 > K##t##_3 ? K##t##_2 : K##t##_3; \
    int m45 = K##t##_4 > K##t##_5 ? K##t##_4 : K##t##_5; \
    int m67 = K##t##_6 > K##t##_7 ? K##t##_6 : K##t##_7; \
    int ma = m01 > m23 ? m01 : m23; int mb = m45 > m67 ? m45 : m67; \
    int mc = ma > mb ? ma : mb; mxK = mxK > mc ? mxK : mc; }
  C4(MXK)
#undef MXK
  mxK = dppmax16i(mxK);

  int lo = -1, hi = mxK, th = 0;
  bool fnd = false;
#pragma unroll 1
  for (int it = 0; it < 32; ++it) {
    const int tm = (lo + hi) >> 1;
    int c = (K32 > tm);
#define CK(t) c += (K##t##_0 > tm) + (K##t##_1 > tm) + (K##t##_2 > tm) + (K##t##_3 > tm) \
             + (K##t##_4 > tm) + (K##t##_5 > tm) + (K##t##_6 > tm) + (K##t##_7 > tm);
    C4(CK)
#undef CK
    c = dppadd16(c);
    if (!fnd) {
      if (c == kk)                   { th = tm; fnd = true; }
      else if (tm <= lo || tm >= hi) { th = lo; fnd = true; }
      else if (c > kk)               lo = tm;
      else                           hi = tm;
    }
    if (__all(fnd)) break;
  }
  if (!fnd) th = lo;

  int h = (int)(ym1 & (unsigned)(K32 > th));
#define HT(t) h += (int)((ym0 >> (8*(t)+0)) & 1u) & (int)(K##t##_0 > th); \
  h += (int)((ym0 >> (8*(t)+1)) & 1u) & (int)(K##t##_1 > th); \
  h += (int)((ym0 >> (8*(t)+2)) & 1u) & (int)(K##t##_2 > th); \
  h += (int)((ym0 >> (8*(t)+3)) & 1u) & (int)(K##t##_3 > th); \
  h += (int)((ym0 >> (8*(t)+4)) & 1u) & (int)(K##t##_4 > th); \
  h += (int)((ym0 >> (8*(t)+5)) & 1u) & (int)(K##t##_5 > th); \
  h += (int)((ym0 >> (8*(t)+6)) & 1u) & (int)(K##t##_6 > th); \
  h += (int)((ym0 >> (8*(t)+7)) & 1u) & (int)(K##t##_7 > th);
  C4(HT)
#undef HT
  h = dppadd16(h);

  float scoreloc = 0.f;
  if (cl == 0) {
    const int hv = h < kk ? h : kk;
    scoreloc = (float)hv / (float)kk;
  }

#pragma unroll
  for (int m = 1; m < 64; m <<= 1) {
    lossloc  += __shfl_xor(lossloc, m, 64);
    scoreloc += __shfl_xor(scoreloc, m, 64);
  }
  if (lane == 0) { redL[w] = lossloc; redS[w] = scoreloc; }
  __syncthreads();
  if (tid == 0) {
    float sl = 0.f, ss = 0.f;
#pragma unroll
    for (int i = 0; i < 16; ++i) { sl += redL[i]; ss += redS[i]; }
    atomicAdd(&accum[0], sl);
    atomicAdd(&accum[1], ss);
  }
}

__global__ void wcvt_kernel(const float* __restrict__ W, short* __restrict__ Wbf,
                            float* __restrict__ ws) {
  if (blockIdx.x == 0 && threadIdx.x == 0) { ws[0] = 0.f; ws[1] = 0.f; }
  int idx = (blockIdx.x * 256 + threadIdx.x) * 4;
  int row = idx >> 9;
  bf16x4 v = {0, 0, 0, 0};
  if (row < CC) {
    f32x4 f = *(const f32x4*)(W + idx);
    v[0]=f2bf(f.x); v[1]=f2bf(f.y); v[2]=f2bf(f.z); v[3]=f2bf(f.w);
  }
  *(bf16x4*)(Wbf + idx) = v;
}

__global__ void init_ws_kernel(float* ws) {
  ws[0] = 0.f;
  ws[1] = 0.f;
}

__global__ void finalize_kernel(const float* __restrict__ ws, float* __restrict__ out) {
  out[0] = (float)((double)ws[0] / ((double)BB * (double)CC));
  out[1] = (float)((double)ws[1] / (double)BB);
}

extern "C" void kernel_launch(void* const* d_in, const int* in_sizes, int n_in,
                              void* d_out, int out_size, void* d_ws, size_t ws_size,
                              hipStream_t stream) {
  const float* x  = (const float*)d_in[0];
  const float* y  = (const float*)d_in[1];
  const float* W  = (const float*)d_in[2];
  const float* b  = (const float*)d_in[3];
  const float* pw = (const float*)d_in[4];
  float* out = (float*)d_out;
  float* ws  = (float*)d_ws;
  short* Wbf = (short*)((char*)d_ws + 64);
  unsigned short* zg = (unsigned short*)((char*)d_ws + 64 + (size_t)NCOLP * DD * 2);

  const size_t need_wbf = 64 + (size_t)NCOLP * DD * 2;                  // 589,888
  const size_t need_z   = need_wbf + (size_t)BB * ZGS * 2;              // +34.6 MB

  if (ws_size >= need_z) {
    // split path: 2-resident GEMM pass + standalone epilogue pass
    hipFuncSetAttribute(reinterpret_cast<const void*>(&gemm_part),
                        hipFuncAttributeMaxDynamicSharedMemorySize, GSMEMB);
    wcvt_kernel<<<dim3(NCOLP * DD / 1024), dim3(256), 0, stream>>>(W, Wbf, ws);
    gemm_part<<<dim3(BB / BM), dim3(512), GSMEMB, stream>>>(x, Wbf, b, zg);
    epi_part<<<dim3(BB / 32), dim3(512), 0, stream>>>(zg, y, pw, ws);
  } else if (ws_size >= need_wbf) {
    void (*kp)(const float*, const float*, const float*, const short*,
               const float*, const float*, float*) = fused_mfma_bce_topk<true>;
    hipFuncSetAttribute(reinterpret_cast<const void*>(kp),
                        hipFuncAttributeMaxDynamicSharedMemorySize, SMEMB);
    wcvt_kernel<<<dim3(NCOLP * DD / 1024), dim3(256), 0, stream>>>(W, Wbf, ws);
    fused_mfma_bce_topk<true><<<dim3(BB / BM), dim3(1024), SMEMB, stream>>>(
        x, y, W, Wbf, b, pw, ws);
  } else {
    void (*kp)(const float*, const float*, const float*, const short*,
               const float*, const float*, float*) = fused_mfma_bce_topk<false>;
    hipFuncSetAttribute(reinterpret_cast<const void*>(kp),
                        hipFuncAttributeMaxDynamicSharedMemorySize, SMEMB);
    init_ws_kernel<<<dim3(1), dim3(1), 0, stream>>>(ws);
    fused_mfma_bce_topk<false><<<dim3(BB / BM), dim3(1024), SMEMB, stream>>>(
        x, y, W, Wbf, b, pw, ws);
  }
  finalize_kernel<<<dim3(1), dim3(1), 0, stream>>>(ws, out);
}